// Round 4
// baseline (167.430 us; speedup 1.0000x reference)
//
#include <hip/hip_runtime.h>
#include <math.h>

// Problem constants
#define B_ 16
#define L_ 512
#define F_ 384
#define H_ 384
#define K_ 3
#define MAX_OUT_ 4096
#define EPS_ 1e-5f

#define APAD (L_ + 2)                 // padded rows per batch (zero guards at 0 and 513)
#define M_TOTAL (B_ * L_)             // 8192 gemm rows
#define KDIM (K_ * F_)                // 1152 gemm K
#define NW (H_ * F_ * K_)             // 442368 weight elems per conv
#define NXE (B_ * L_ * F_)            // 3145728 activation elems
#define NXP (B_ * APAD * F_)          // 3158016 padded activation elems

typedef __attribute__((ext_vector_type(8))) short bf16x8;   // 8 bf16 = 4 VGPR
typedef __attribute__((ext_vector_type(4))) float f32x4;

// ---------------------------------------------------------------------------
// bf16 split helpers: v = hi + lo with RNE rounding (3-term product error ~2^-17)
// ---------------------------------------------------------------------------
__device__ inline unsigned short bf16_rne(float v) {
    unsigned int u = __float_as_uint(v);
    unsigned int r = (u + 0x7fffu + ((u >> 16) & 1u)) >> 16;
    return (unsigned short)r;
}
__device__ inline void bf16_split(float v, unsigned short& hi, unsigned short& lo) {
    hi = bf16_rne(v);
    float hf = __uint_as_float(((unsigned int)hi) << 16);
    lo = bf16_rne(v - hf);
}

// ---------------------------------------------------------------------------
// Kernel 1: per-batch cumsum of target + searchsorted index table (unchanged).
// ---------------------------------------------------------------------------
__global__ void k_scan_idx(const int* __restrict__ target, int* __restrict__ idx) {
    __shared__ int e[L_];
    const int b = blockIdx.x;
    const int tid = threadIdx.x;   // blockDim = 512 = L_
    e[tid] = target[b * L_ + tid];
    __syncthreads();
    for (int off = 1; off < L_; off <<= 1) {
        int add = (tid >= off) ? e[tid - off] : 0;
        __syncthreads();
        e[tid] += add;
        __syncthreads();
    }
    const int total = e[L_ - 1];
    for (int t = tid; t < MAX_OUT_; t += L_) {
        int lo = 0, hi = L_;
        while (lo < hi) {
            int m = (lo + hi) >> 1;
            if (e[m] <= t) lo = m + 1; else hi = m;
        }
        int v = (t < total) ? min(lo, L_ - 1) : -1;
        idx[b * MAX_OUT_ + t] = v;
    }
}

// ---------------------------------------------------------------------------
// Kernel 2: prep — split input x into PADDED bf16 hi/lo planes [B][514][F];
// transpose+split both conv weights to [h][tap*384+f] hi/lo planes.
// ---------------------------------------------------------------------------
__global__ void k_prep(const float* __restrict__ x,
                       const float* __restrict__ w1, const float* __restrict__ w2,
                       unsigned short* __restrict__ xh, unsigned short* __restrict__ xl,
                       unsigned short* __restrict__ w1h, unsigned short* __restrict__ w1l,
                       unsigned short* __restrict__ w2h, unsigned short* __restrict__ w2l) {
    const int NX4 = NXE / 4;               // 786432 float4s of x
    const int G4 = B_ * 2 * (F_ / 4);      // 3072 guard ushort4s per plane
    const int total = NX4 + G4 + 2 * NW;
    for (int i = blockIdx.x * blockDim.x + threadIdx.x; i < total;
         i += gridDim.x * blockDim.x) {
        if (i < NX4) {
            const int fi = i % (F_ / 4);
            const int row = i / (F_ / 4);          // global row 0..8191
            const int b = row >> 9;
            const int l = row & (L_ - 1);
            const int po = (b * APAD + l + 1) * (F_ / 4) + fi;
            float4 v = ((const float4*)x)[i];
            ushort4 hv, lv;
            bf16_split(v.x, hv.x, lv.x);
            bf16_split(v.y, hv.y, lv.y);
            bf16_split(v.z, hv.z, lv.z);
            bf16_split(v.w, hv.w, lv.w);
            ((ushort4*)xh)[po] = hv;
            ((ushort4*)xl)[po] = lv;
        } else if (i < NX4 + G4) {
            const int j = i - NX4;
            const int b = j / (2 * (F_ / 4));
            const int r = j % (2 * (F_ / 4));
            const int grow = (r < (F_ / 4)) ? 0 : (APAD - 1);
            const int fi = r % (F_ / 4);
            const int po = (b * APAD + grow) * (F_ / 4) + fi;
            const ushort4 z = {0, 0, 0, 0};
            ((ushort4*)xh)[po] = z;
            ((ushort4*)xl)[po] = z;
        } else {
            int j = i - NX4 - G4;
            const float* w = (j < NW) ? w1 : w2;
            unsigned short* ohp = (j < NW) ? w1h : w2h;
            unsigned short* olp = (j < NW) ? w1l : w2l;
            int o = (j < NW) ? j : j - NW;
            int h = o / KDIM;
            int rem = o - h * KDIM;
            int k = rem / F_;                      // tap
            int f = rem - k * F_;
            unsigned short hi, lo;
            bf16_split(w[(h * F_ + f) * K_ + k], hi, lo);
            ohp[o] = hi;
            olp[o] = lo;
        }
    }
}

// ---------------------------------------------------------------------------
// Kernel 3: conv-as-GEMM via split-bf16 MFMA (3 terms: hh + hl + lh).
// 64x64 tile, split-K-4, 4 waves. NEW structure: per-wave-private LDS double
// buffers filled by global_load_lds (no VGPR dest -> compiler cannot sink the
// prefetch), counted s_waitcnt vmcnt(16), NO barriers in the K-loop (buffers
// are wave-private). LDS layout is chunk-major ([g][c][r], lane = c*16+r) so
// every fragment ds_read_b128 is a linear 1KB wave access: conflict-free, and
// the MFMA fragment mapping (row=lane&15, kchunk=lane>>4) matches exactly.
// 128 KB LDS -> 1 block/CU by design; reduction LDS aliases stage buffers.
// ---------------------------------------------------------------------------
typedef __attribute__((address_space(3))) char lds_char;
typedef const __attribute__((address_space(1))) char g_char;

#define GLDS(gsrc, ldst)                                                   \
    __builtin_amdgcn_global_load_lds((g_char*)(gsrc), (lds_char*)(ldst), 16, 0, 0)

// stage K-step S into buffer D (16 gload_lds, offsets are compile-time)
#define STAGE(S, D)                                                        \
    _Pragma("unroll")                                                      \
    for (int g = 0; g < 4; ++g) {                                          \
        GLDS(gah[g] + (S) * 32, wb + (D) * 16384 +         g * 1024);      \
        GLDS(gal[g] + (S) * 32, wb + (D) * 16384 + 4096  + g * 1024);      \
        GLDS(gbh[g] + (S) * 32, wb + (D) * 16384 + 8192  + g * 1024);      \
        GLDS(gbl[g] + (S) * 32, wb + (D) * 16384 + 12288 + g * 1024);      \
    }

// term-major: 16 independent MFMAs between dependent writes to the same acc
#define MFMAS(AH, AL, BH, BL)                                              \
    _Pragma("unroll")                                                      \
    for (int ni = 0; ni < 4; ++ni)                                         \
        _Pragma("unroll")                                                  \
        for (int mi = 0; mi < 4; ++mi)                                     \
            acc[mi][ni] = __builtin_amdgcn_mfma_f32_16x16x32_bf16(         \
                AH[mi], BH[ni], acc[mi][ni], 0, 0, 0);                     \
    _Pragma("unroll")                                                      \
    for (int ni = 0; ni < 4; ++ni)                                         \
        _Pragma("unroll")                                                  \
        for (int mi = 0; mi < 4; ++mi)                                     \
            acc[mi][ni] = __builtin_amdgcn_mfma_f32_16x16x32_bf16(         \
                AH[mi], BL[ni], acc[mi][ni], 0, 0, 0);                     \
    _Pragma("unroll")                                                      \
    for (int ni = 0; ni < 4; ++ni)                                         \
        _Pragma("unroll")                                                  \
        for (int mi = 0; mi < 4; ++mi)                                     \
            acc[mi][ni] = __builtin_amdgcn_mfma_f32_16x16x32_bf16(         \
                AL[mi], BH[ni], acc[mi][ni], 0, 0, 0);

#define SB __builtin_amdgcn_sched_barrier(0)

// one K-iteration: counted wait -> 16 ds_read -> lgkm(0) -> restage -> 48 MFMA
#define KITER(S, NWAIT, ...)                                               \
    {                                                                      \
        asm volatile("s_waitcnt vmcnt(" #NWAIT ")" ::: "memory");          \
        SB;                                                                \
        _Pragma("unroll")                                                  \
        for (int g = 0; g < 4; ++g) {                                      \
            Ah[g] = *(const bf16x8*)(wb + ((S) & 1) * 16384 +         g * 1024 + l16); \
            Al[g] = *(const bf16x8*)(wb + ((S) & 1) * 16384 + 4096  + g * 1024 + l16); \
            Bh[g] = *(const bf16x8*)(wb + ((S) & 1) * 16384 + 8192  + g * 1024 + l16); \
            Bl[g] = *(const bf16x8*)(wb + ((S) & 1) * 16384 + 12288 + g * 1024 + l16); \
        }                                                                  \
        SB;                                                                \
        asm volatile("s_waitcnt lgkmcnt(0)" ::: "memory");                 \
        SB;                                                                \
        __VA_ARGS__;                                                       \
        SB;                                                                \
        MFMAS(Ah, Al, Bh, Bl);                                             \
        SB;                                                                \
    }

__global__ __launch_bounds__(256, 1) void k_gemm(
        const unsigned short* __restrict__ Ahi,
        const unsigned short* __restrict__ Alo,
        const unsigned short* __restrict__ Bhi,
        const unsigned short* __restrict__ Blo,
        float* __restrict__ C) {
    __shared__ __align__(16) char smem[131072];    // 4 waves x 2 bufs x 16 KB
    const int lane = threadIdx.x & 63;
    const int wv = threadIdx.x >> 6;       // wave 0..3 = K-slice
    const int r0 = blockIdx.x * 64;
    const int h0 = blockIdx.y * 64;
    const int k0 = wv * (KDIM / 4);        // 288 per wave
    const int b = r0 >> 9;                 // 64-row tiles never straddle batches
    const int l = r0 & (L_ - 1);

    char* wb = smem + (wv << 15);          // per-wave 32 KB region
    const int l16 = lane * 16;

    // per-lane global base pointers for staging: lane = (chunk c)*16 + (row r)
    const int sr = lane & 15;
    const int sc = lane >> 4;
    const unsigned short *gah[4], *gal[4], *gbh[4], *gbl[4];
#pragma unroll
    for (int g = 0; g < 4; ++g) {
        const int ar = (b * APAD + l + g * 16 + sr) * F_ + k0 + sc * 8;
        const int br = (h0 + g * 16 + sr) * KDIM + k0 + sc * 8;
        gah[g] = Ahi + ar;  gal[g] = Alo + ar;
        gbh[g] = Bhi + br;  gbl[g] = Blo + br;
    }

    const f32x4 z4 = {0.f, 0.f, 0.f, 0.f};
    f32x4 acc[4][4];
#pragma unroll
    for (int i = 0; i < 4; ++i)
#pragma unroll
        for (int j = 0; j < 4; ++j) acc[i][j] = z4;

    bf16x8 Ah[4], Al[4], Bh[4], Bl[4];

    // prologue: two K-steps in flight
    STAGE(0, 0); SB;
    STAGE(1, 1); SB;

    KITER(0, 16, STAGE(2, 0));
    KITER(1, 16, STAGE(3, 1));
    KITER(2, 16, STAGE(4, 0));
    KITER(3, 16, STAGE(5, 1));
    KITER(4, 16, STAGE(6, 0));
    KITER(5, 16, STAGE(7, 1));
    KITER(6, 16, STAGE(8, 0));
    KITER(7, 16, (void)0);
    KITER(8, 0, (void)0);

    // ---- split-K reduction, 2 pairwise rounds (reduction LDS aliases the
    // stage buffers; safe after barrier since all staged data is consumed) ----
    // C/D layout: col = lane&15, row = (lane>>4)*4 + reg.
    float (*red)[64][66] = (float (*)[64][66])smem;   // [2][64][66]
    const int lr = lane & 15;
    const int rb = (lane >> 4) * 4;
    __syncthreads();
    if (wv >= 2) {
#pragma unroll
        for (int mi = 0; mi < 4; ++mi)
#pragma unroll
            for (int ni = 0; ni < 4; ++ni)
#pragma unroll
                for (int r = 0; r < 4; ++r)
                    red[wv - 2][mi * 16 + rb + r][ni * 16 + lr] = acc[mi][ni][r];
    }
    __syncthreads();
    if (wv < 2) {
#pragma unroll
        for (int mi = 0; mi < 4; ++mi)
#pragma unroll
            for (int ni = 0; ni < 4; ++ni)
#pragma unroll
                for (int r = 0; r < 4; ++r)
                    acc[mi][ni][r] += red[wv][mi * 16 + rb + r][ni * 16 + lr];
    }
    __syncthreads();
    // round 2: wave1 publishes rows 0..31, wave0 publishes rows 32..63
    if (wv == 1) {
#pragma unroll
        for (int mi = 0; mi < 2; ++mi)
#pragma unroll
            for (int ni = 0; ni < 4; ++ni)
#pragma unroll
                for (int r = 0; r < 4; ++r)
                    red[0][mi * 16 + rb + r][ni * 16 + lr] = acc[mi][ni][r];
    }
    if (wv == 0) {
#pragma unroll
        for (int mi = 2; mi < 4; ++mi)
#pragma unroll
            for (int ni = 0; ni < 4; ++ni)
#pragma unroll
                for (int r = 0; r < 4; ++r)
                    red[0][mi * 16 + rb + r][ni * 16 + lr] = acc[mi][ni][r];
    }
    __syncthreads();
    if (wv == 0) {     // stores rows 0..31
#pragma unroll
        for (int mi = 0; mi < 2; ++mi)
#pragma unroll
            for (int ni = 0; ni < 4; ++ni)
#pragma unroll
                for (int r = 0; r < 4; ++r) {
                    const int rr = mi * 16 + rb + r;
                    const int cc = ni * 16 + lr;
                    C[(r0 + rr) * H_ + h0 + cc] = acc[mi][ni][r] + red[0][rr][cc];
                }
    }
    if (wv == 1) {     // stores rows 32..63
#pragma unroll
        for (int mi = 2; mi < 4; ++mi)
#pragma unroll
            for (int ni = 0; ni < 4; ++ni)
#pragma unroll
                for (int r = 0; r < 4; ++r) {
                    const int rr = mi * 16 + rb + r;
                    const int cc = ni * 16 + lr;
                    C[(r0 + rr) * H_ + h0 + cc] = acc[mi][ni][r] + red[0][rr][cc];
                }
    }
}

// ---------------------------------------------------------------------------
// Kernel 4: bias + LayerNorm + ReLU over raw conv1 output, re-split to PADDED
// bf16 hi/lo planes for conv2's A operand. One wave per row (384 channels).
// ---------------------------------------------------------------------------
__global__ __launch_bounds__(256) void k_lnrelu(
        const float* __restrict__ c, const float* __restrict__ cb,
        const float* __restrict__ g, const float* __restrict__ bt,
        unsigned short* __restrict__ oh, unsigned short* __restrict__ ol) {
    const int row = blockIdx.x * 4 + (threadIdx.x >> 6);
    const int lane = threadIdx.x & 63;
    const float* cr = c + (long)row * H_;
    float2 dv[3];
    dv[0] = ((const float2*)cr)[lane];
    dv[1] = ((const float2*)cr)[lane + 64];
    dv[2] = ((const float2*)cr)[lane + 128];
#pragma unroll
    for (int p = 0; p < 3; ++p) {
        const int ch = 2 * (lane + 64 * p);
        dv[p].x += cb[ch];
        dv[p].y += cb[ch + 1];
    }
    float s = dv[0].x + dv[0].y + dv[1].x + dv[1].y + dv[2].x + dv[2].y;
    float s2 = dv[0].x * dv[0].x + dv[0].y * dv[0].y + dv[1].x * dv[1].x
             + dv[1].y * dv[1].y + dv[2].x * dv[2].x + dv[2].y * dv[2].y;
    for (int off = 32; off >= 1; off >>= 1) {
        s += __shfl_xor(s, off);
        s2 += __shfl_xor(s2, off);
    }
    const float mu = s * (1.f / H_);
    const float var = s2 * (1.f / H_) - mu * mu;
    const float rs = rsqrtf(var + EPS_);
    const int bpo = (row >> 9) * APAD + (row & (L_ - 1)) + 1;   // padded row
    const long po = (long)bpo * H_;
#pragma unroll
    for (int p = 0; p < 3; ++p) {
        const int ch = 2 * (lane + 64 * p);
        float r0 = fmaxf((dv[p].x - mu) * rs * g[ch] + bt[ch], 0.f);
        float r1 = fmaxf((dv[p].y - mu) * rs * g[ch + 1] + bt[ch + 1], 0.f);
        ushort2 hv, lv;
        bf16_split(r0, hv.x, lv.x);
        bf16_split(r1, hv.y, lv.y);
        *(ushort2*)(oh + po + ch) = hv;
        *(ushort2*)(ol + po + ch) = lv;
    }
}

// ---------------------------------------------------------------------------
// Kernel 5: bias + LayerNorm + ReLU + linear + ReLU + exp -> durations.
// ---------------------------------------------------------------------------
__global__ __launch_bounds__(256) void k_fin(
        const float* __restrict__ c, const float* __restrict__ cb,
        const float* __restrict__ g, const float* __restrict__ bt,
        const float* __restrict__ lw, const float* __restrict__ lb,
        float* __restrict__ dur) {
    const int row = blockIdx.x * 4 + (threadIdx.x >> 6);
    const int lane = threadIdx.x & 63;
    const float* cr = c + (long)row * F_;
    float2 dv[3];
    dv[0] = ((const float2*)cr)[lane];
    dv[1] = ((const float2*)cr)[lane + 64];
    dv[2] = ((const float2*)cr)[lane + 128];
#pragma unroll
    for (int p = 0; p < 3; ++p) {
        const int ch = 2 * (lane + 64 * p);
        dv[p].x += cb[ch];
        dv[p].y += cb[ch + 1];
    }
    float s = dv[0].x + dv[0].y + dv[1].x + dv[1].y + dv[2].x + dv[2].y;
    float s2 = dv[0].x * dv[0].x + dv[0].y * dv[0].y + dv[1].x * dv[1].x
             + dv[1].y * dv[1].y + dv[2].x * dv[2].x + dv[2].y * dv[2].y;
    for (int off = 32; off >= 1; off >>= 1) {
        s += __shfl_xor(s, off);
        s2 += __shfl_xor(s2, off);
    }
    const float mu = s * (1.f / F_);
    const float var = s2 * (1.f / F_) - mu * mu;
    const float rs = rsqrtf(var + EPS_);
    float dot = 0.f;
#pragma unroll
    for (int p = 0; p < 3; ++p) {
        const int ch = 2 * (lane + 64 * p);
        float r0 = fmaxf((dv[p].x - mu) * rs * g[ch] + bt[ch], 0.f);
        float r1 = fmaxf((dv[p].y - mu) * rs * g[ch + 1] + bt[ch + 1], 0.f);
        dot += r0 * lw[ch] + r1 * lw[ch + 1];
    }
    for (int off = 32; off >= 1; off >>= 1) dot += __shfl_xor(dot, off);
    if (lane == 0) dur[row] = expf(fmaxf(dot + lb[0], 0.f));
}

// ---------------------------------------------------------------------------
// Kernel 6: length-regulate gather (memory bound, unchanged).
// ---------------------------------------------------------------------------
__global__ void k_gather(const float4* __restrict__ x, const int* __restrict__ idx,
                         float4* __restrict__ out) {
    const int F4 = F_ / 4;                        // 96
    const int total = B_ * MAX_OUT_ * F4;
    for (int i = blockIdx.x * blockDim.x + threadIdx.x; i < total;
         i += gridDim.x * blockDim.x) {
        int row = i / F4;
        int f4 = i - row * F4;
        int t = row % MAX_OUT_;
        int b = row / MAX_OUT_;
        int id = idx[b * MAX_OUT_ + t];
        float4 v = make_float4(0.f, 0.f, 0.f, 0.f);
        if (id >= 0) v = x[((long)b * L_ + id) * F4 + f4];
        out[i] = v;
    }
}

// ---------------------------------------------------------------------------
extern "C" void kernel_launch(void* const* d_in, const int* in_sizes, int n_in,
                              void* d_out, int out_size, void* d_ws, size_t ws_size,
                              hipStream_t stream) {
    const float* input   = (const float*)d_in[0];
    const int*   target  = (const int*)d_in[1];
    const float* conv1_w = (const float*)d_in[2];
    const float* conv1_b = (const float*)d_in[3];
    const float* ln1_g   = (const float*)d_in[4];
    const float* ln1_b   = (const float*)d_in[5];
    const float* conv2_w = (const float*)d_in[6];
    const float* conv2_b = (const float*)d_in[7];
    const float* ln2_g   = (const float*)d_in[8];
    const float* ln2_b   = (const float*)d_in[9];
    const float* lin_w   = (const float*)d_in[10];
    const float* lin_b   = (const float*)d_in[11];

    float* out0 = (float*)d_out;                                  // [B, 4096, F]
    float* dur  = out0 + (size_t)B_ * MAX_OUT_ * F_;              // [B, L]
    float* c    = out0;   // raw conv outputs scratched in out0 (overwritten by gather)

    // workspace: idx 256KB + padded x/h1 planes 12.63MB + weight planes 3.54MB
    char* ws = (char*)d_ws;
    int* idx = (int*)ws;                                          // 262144 B
    unsigned short* xh  = (unsigned short*)(ws + 262144);
    unsigned short* xl  = xh + NXP;
    unsigned short* w1h = xl + NXP;
    unsigned short* w1l = w1h + NW;
    unsigned short* w2h = w1l + NW;
    unsigned short* w2l = w2h + NW;

    hipLaunchKernelGGL(k_scan_idx, dim3(B_), dim3(L_), 0, stream, target, idx);
    hipLaunchKernelGGL(k_prep, dim3(2048), dim3(256), 0, stream,
                       input, conv1_w, conv2_w, xh, xl, w1h, w1l, w2h, w2l);
    // conv1: raw output into out0 scratch
    hipLaunchKernelGGL(k_gemm, dim3(M_TOTAL / 64, H_ / 64), dim3(256), 0, stream,
                       xh, xl, w1h, w1l, c);
    // bias+LN+ReLU, re-split into the (now dead) padded x planes
    hipLaunchKernelGGL(k_lnrelu, dim3(M_TOTAL / 4), dim3(256), 0, stream,
                       c, conv1_b, ln1_g, ln1_b, xh, xl);
    // conv2: raw output into out0 scratch
    hipLaunchKernelGGL(k_gemm, dim3(M_TOTAL / 64, H_ / 64), dim3(256), 0, stream,
                       xh, xl, w2h, w2l, c);
    // bias+LN+ReLU+linear+ReLU+exp -> durations
    hipLaunchKernelGGL(k_fin, dim3(M_TOTAL / 4), dim3(256), 0, stream,
                       c, conv2_b, ln2_g, ln2_b, lin_w, lin_b, dur);
    // finally overwrite out0 with the gather
    hipLaunchKernelGGL(k_gather, dim3(4096), dim3(256), 0, stream,
                       (const float4*)input, idx, (float4*)out0);
}

// Round 5
// 162.769 us; speedup vs baseline: 1.0286x; 1.0286x over previous
//
#include <hip/hip_runtime.h>
#include <math.h>

// Problem constants
#define B_ 16
#define L_ 512
#define F_ 384
#define H_ 384
#define K_ 3
#define MAX_OUT_ 4096
#define EPS_ 1e-5f

#define APAD (L_ + 2)                 // padded rows per batch (zero guards at 0 and 513)
#define M_TOTAL (B_ * L_)             // 8192 gemm rows
#define KDIM (K_ * F_)                // 1152 gemm K
#define NW (H_ * F_ * K_)             // 442368 weight elems per conv
#define NXE (B_ * L_ * F_)            // 3145728 activation elems
#define NXP (B_ * APAD * F_)          // 3158016 padded activation elems

typedef __attribute__((ext_vector_type(8))) short bf16x8;   // 8 bf16 = 4 VGPR
typedef __attribute__((ext_vector_type(4))) float f32x4;

// ---------------------------------------------------------------------------
// bf16 split helpers: v = hi + lo with RNE rounding (3-term product error ~2^-17)
// ---------------------------------------------------------------------------
__device__ inline unsigned short bf16_rne(float v) {
    unsigned int u = __float_as_uint(v);
    unsigned int r = (u + 0x7fffu + ((u >> 16) & 1u)) >> 16;
    return (unsigned short)r;
}
__device__ inline void bf16_split(float v, unsigned short& hi, unsigned short& lo) {
    hi = bf16_rne(v);
    float hf = __uint_as_float(((unsigned int)hi) << 16);
    lo = bf16_rne(v - hf);
}

// ---------------------------------------------------------------------------
// Kernel 1: per-batch cumsum of target + searchsorted index table (unchanged).
// ---------------------------------------------------------------------------
__global__ void k_scan_idx(const int* __restrict__ target, int* __restrict__ idx) {
    __shared__ int e[L_];
    const int b = blockIdx.x;
    const int tid = threadIdx.x;   // blockDim = 512 = L_
    e[tid] = target[b * L_ + tid];
    __syncthreads();
    for (int off = 1; off < L_; off <<= 1) {
        int add = (tid >= off) ? e[tid - off] : 0;
        __syncthreads();
        e[tid] += add;
        __syncthreads();
    }
    const int total = e[L_ - 1];
    for (int t = tid; t < MAX_OUT_; t += L_) {
        int lo = 0, hi = L_;
        while (lo < hi) {
            int m = (lo + hi) >> 1;
            if (e[m] <= t) lo = m + 1; else hi = m;
        }
        int v = (t < total) ? min(lo, L_ - 1) : -1;
        idx[b * MAX_OUT_ + t] = v;
    }
}

// ---------------------------------------------------------------------------
// Kernel 2: prep — split input x into PADDED bf16 hi/lo planes [B][514][F];
// transpose+split both conv weights to [h][tap*384+f] hi/lo planes.
// ---------------------------------------------------------------------------
__global__ void k_prep(const float* __restrict__ x,
                       const float* __restrict__ w1, const float* __restrict__ w2,
                       unsigned short* __restrict__ xh, unsigned short* __restrict__ xl,
                       unsigned short* __restrict__ w1h, unsigned short* __restrict__ w1l,
                       unsigned short* __restrict__ w2h, unsigned short* __restrict__ w2l) {
    const int NX4 = NXE / 4;               // 786432 float4s of x
    const int G4 = B_ * 2 * (F_ / 4);      // 3072 guard ushort4s per plane
    const int total = NX4 + G4 + 2 * NW;
    for (int i = blockIdx.x * blockDim.x + threadIdx.x; i < total;
         i += gridDim.x * blockDim.x) {
        if (i < NX4) {
            const int fi = i % (F_ / 4);
            const int row = i / (F_ / 4);          // global row 0..8191
            const int b = row >> 9;
            const int l = row & (L_ - 1);
            const int po = (b * APAD + l + 1) * (F_ / 4) + fi;
            float4 v = ((const float4*)x)[i];
            ushort4 hv, lv;
            bf16_split(v.x, hv.x, lv.x);
            bf16_split(v.y, hv.y, lv.y);
            bf16_split(v.z, hv.z, lv.z);
            bf16_split(v.w, hv.w, lv.w);
            ((ushort4*)xh)[po] = hv;
            ((ushort4*)xl)[po] = lv;
        } else if (i < NX4 + G4) {
            const int j = i - NX4;
            const int b = j / (2 * (F_ / 4));
            const int r = j % (2 * (F_ / 4));
            const int grow = (r < (F_ / 4)) ? 0 : (APAD - 1);
            const int fi = r % (F_ / 4);
            const int po = (b * APAD + grow) * (F_ / 4) + fi;
            const ushort4 z = {0, 0, 0, 0};
            ((ushort4*)xh)[po] = z;
            ((ushort4*)xl)[po] = z;
        } else {
            int j = i - NX4 - G4;
            const float* w = (j < NW) ? w1 : w2;
            unsigned short* ohp = (j < NW) ? w1h : w2h;
            unsigned short* olp = (j < NW) ? w1l : w2l;
            int o = (j < NW) ? j : j - NW;
            int h = o / KDIM;
            int rem = o - h * KDIM;
            int k = rem / F_;                      // tap
            int f = rem - k * F_;
            unsigned short hi, lo;
            bf16_split(w[(h * F_ + f) * K_ + k], hi, lo);
            ohp[o] = hi;
            olp[o] = lo;
        }
    }
}

// ---------------------------------------------------------------------------
// Kernel 3: conv-as-GEMM via split-bf16 MFMA (3 terms: hh + hl + lh).
// m97-style structure: 64x64 tile, FULL K per block (no split-K, no reduction
// epilogue), 4 waves each owning a 32x32 quadrant (wr=wv>>1, wc=wv&1).
// Per K-step (BK=32) the block stages 16 KB (A,B x hi,lo) into shared LDS via
// 16 global_load_lds (4 per wave: wave wv stages k-chunk wv of each plane).
// LDS is chunk-major: plane[4 chunks][64 rows]x16B -> gload_lds's lane*16
// write order IS the layout, and every fragment ds_read_b128 is a linear
// 1 KB wave access (conflict-free, no swizzle needed).
// Double-buffered 2x16 KB = 32 KB -> 4 blocks/CU (16 waves/CU) so wave-level
// TLP hides L2/LDS latency (the thing rounds 2-4 could not achieve).
// ---------------------------------------------------------------------------
typedef __attribute__((address_space(3))) char lds_char;
typedef const __attribute__((address_space(1))) char g_char;

#define GLDS(gsrc, ldst)                                                   \
    __builtin_amdgcn_global_load_lds((g_char*)(gsrc), (lds_char*)(ldst), 16, 0, 0)

// stage K-step (pointer base + KOFF elems) into buffer BUF; 4 gload_lds/wave
#define ST(BUF, KOFF)                                                      \
    GLDS(pAh + (KOFF), smem + (BUF) * 16384 +         dst);                \
    GLDS(pAl + (KOFF), smem + (BUF) * 16384 +  4096 + dst);               \
    GLDS(pBh + (KOFF), smem + (BUF) * 16384 +  8192 + dst);               \
    GLDS(pBl + (KOFF), smem + (BUF) * 16384 + 12288 + dst);

// read this wave's 8 fragments from buffer BUF (linear 1KB wave accesses)
#define RD(BUF)                                                            \
    ah[0] = *(const bf16x8*)(smem + (BUF) * 16384 +         aoff);         \
    ah[1] = *(const bf16x8*)(smem + (BUF) * 16384 +         aoff + 256);   \
    al[0] = *(const bf16x8*)(smem + (BUF) * 16384 +  4096 + aoff);         \
    al[1] = *(const bf16x8*)(smem + (BUF) * 16384 +  4096 + aoff + 256);   \
    bh[0] = *(const bf16x8*)(smem + (BUF) * 16384 +  8192 + boff);         \
    bh[1] = *(const bf16x8*)(smem + (BUF) * 16384 +  8192 + boff + 256);   \
    bl[0] = *(const bf16x8*)(smem + (BUF) * 16384 + 12288 + boff);         \
    bl[1] = *(const bf16x8*)(smem + (BUF) * 16384 + 12288 + boff + 256);

// 12 MFMAs, term-major (4 independent between dependent writes to same acc)
#define MM()                                                               \
    _Pragma("unroll")                                                      \
    for (int ni = 0; ni < 2; ++ni)                                         \
        _Pragma("unroll")                                                  \
        for (int mi = 0; mi < 2; ++mi)                                     \
            acc[mi][ni] = __builtin_amdgcn_mfma_f32_16x16x32_bf16(         \
                ah[mi], bh[ni], acc[mi][ni], 0, 0, 0);                     \
    _Pragma("unroll")                                                      \
    for (int ni = 0; ni < 2; ++ni)                                         \
        _Pragma("unroll")                                                  \
        for (int mi = 0; mi < 2; ++mi)                                     \
            acc[mi][ni] = __builtin_amdgcn_mfma_f32_16x16x32_bf16(         \
                ah[mi], bl[ni], acc[mi][ni], 0, 0, 0);                     \
    _Pragma("unroll")                                                      \
    for (int ni = 0; ni < 2; ++ni)                                         \
        _Pragma("unroll")                                                  \
        for (int mi = 0; mi < 2; ++mi)                                     \
            acc[mi][ni] = __builtin_amdgcn_mfma_f32_16x16x32_bf16(         \
                al[mi], bh[ni], acc[mi][ni], 0, 0, 0);

__global__ __launch_bounds__(256, 4) void k_gemm(
        const unsigned short* __restrict__ Ahi,
        const unsigned short* __restrict__ Alo,
        const unsigned short* __restrict__ Bhi,
        const unsigned short* __restrict__ Blo,
        float* __restrict__ C) {
    __shared__ __align__(1024) char smem[32768];   // 2 bufs x 16 KB
    const int lane = threadIdx.x & 63;
    const int wv = threadIdx.x >> 6;       // 4 waves
    const int wr = wv >> 1;                // wave row quadrant (0,1)
    const int wc = wv & 1;                 // wave col quadrant (0,1)
    const int r0 = blockIdx.x * 64;
    const int h0 = blockIdx.y * 64;
    const int b = r0 >> 9;                 // 64-row tiles never straddle batches
    const int l0 = r0 & (L_ - 1);

    // staging: wave wv stages k-chunk wv (k-offset wv*8) of each plane; lane=row
    const unsigned short* pAh = Ahi + (b * APAD + l0 + lane) * F_ + wv * 8;
    const unsigned short* pAl = Alo + (b * APAD + l0 + lane) * F_ + wv * 8;
    const unsigned short* pBh = Bhi + (h0 + lane) * KDIM + wv * 8;
    const unsigned short* pBl = Blo + (h0 + lane) * KDIM + wv * 8;
    const int dst = wv * 1024;             // LDS chunk slot within each plane

    // fragment read offsets: fr = row-in-frag, fc = k-chunk
    const int fr = lane & 15;
    const int fc = lane >> 4;
    const int aoff = fc * 1024 + (wr * 32 + fr) * 16;
    const int boff = fc * 1024 + (wc * 32 + fr) * 16;

    const f32x4 z4 = {0.f, 0.f, 0.f, 0.f};
    f32x4 acc[2][2];
#pragma unroll
    for (int i = 0; i < 2; ++i)
#pragma unroll
        for (int j = 0; j < 2; ++j) acc[i][j] = z4;

    bf16x8 ah[2], al[2], bh[2], bl[2];

    // 36 K-steps of 32, double-buffered; 1 barrier per K-step (m97 pattern:
    // compiler inserts the vmcnt/lgkmcnt drains before each s_barrier).
    ST(0, 0);
    __syncthreads();
#pragma unroll 1
    for (int i = 0; i < 18; ++i) {
        ST(1, 32);                 // stage step 2i+1 while computing 2i
        RD(0);
        MM();
        __syncthreads();           // buf1 staged; everyone done with buf0
        if (i != 17) { ST(0, 64); }  // stage step 2i+2 while computing 2i+1
        RD(1);
        MM();
        pAh += 64; pAl += 64; pBh += 64; pBl += 64;
        __syncthreads();           // buf0 staged; everyone done with buf1
    }

    // direct C-write: C/D layout col = lane&15, row = (lane>>4)*4 + reg
    const int rb = (lane >> 4) * 4;
#pragma unroll
    for (int mi = 0; mi < 2; ++mi)
#pragma unroll
        for (int ni = 0; ni < 2; ++ni)
#pragma unroll
            for (int r = 0; r < 4; ++r)
                C[(r0 + wr * 32 + mi * 16 + rb + r) * H_ +
                  h0 + wc * 32 + ni * 16 + fr] = acc[mi][ni][r];
}

// ---------------------------------------------------------------------------
// Kernel 4: bias + LayerNorm + ReLU over raw conv1 output, re-split to PADDED
// bf16 hi/lo planes for conv2's A operand. One wave per row (384 channels).
// ---------------------------------------------------------------------------
__global__ __launch_bounds__(256) void k_lnrelu(
        const float* __restrict__ c, const float* __restrict__ cb,
        const float* __restrict__ g, const float* __restrict__ bt,
        unsigned short* __restrict__ oh, unsigned short* __restrict__ ol) {
    const int row = blockIdx.x * 4 + (threadIdx.x >> 6);
    const int lane = threadIdx.x & 63;
    const float* cr = c + (long)row * H_;
    float2 dv[3];
    dv[0] = ((const float2*)cr)[lane];
    dv[1] = ((const float2*)cr)[lane + 64];
    dv[2] = ((const float2*)cr)[lane + 128];
#pragma unroll
    for (int p = 0; p < 3; ++p) {
        const int ch = 2 * (lane + 64 * p);
        dv[p].x += cb[ch];
        dv[p].y += cb[ch + 1];
    }
    float s = dv[0].x + dv[0].y + dv[1].x + dv[1].y + dv[2].x + dv[2].y;
    float s2 = dv[0].x * dv[0].x + dv[0].y * dv[0].y + dv[1].x * dv[1].x
             + dv[1].y * dv[1].y + dv[2].x * dv[2].x + dv[2].y * dv[2].y;
    for (int off = 32; off >= 1; off >>= 1) {
        s += __shfl_xor(s, off);
        s2 += __shfl_xor(s2, off);
    }
    const float mu = s * (1.f / H_);
    const float var = s2 * (1.f / H_) - mu * mu;
    const float rs = rsqrtf(var + EPS_);
    const int bpo = (row >> 9) * APAD + (row & (L_ - 1)) + 1;   // padded row
    const long po = (long)bpo * H_;
#pragma unroll
    for (int p = 0; p < 3; ++p) {
        const int ch = 2 * (lane + 64 * p);
        float r0 = fmaxf((dv[p].x - mu) * rs * g[ch] + bt[ch], 0.f);
        float r1 = fmaxf((dv[p].y - mu) * rs * g[ch + 1] + bt[ch + 1], 0.f);
        ushort2 hv, lv;
        bf16_split(r0, hv.x, lv.x);
        bf16_split(r1, hv.y, lv.y);
        *(ushort2*)(oh + po + ch) = hv;
        *(ushort2*)(ol + po + ch) = lv;
    }
}

// ---------------------------------------------------------------------------
// Kernel 5: bias + LayerNorm + ReLU + linear + ReLU + exp -> durations.
// ---------------------------------------------------------------------------
__global__ __launch_bounds__(256) void k_fin(
        const float* __restrict__ c, const float* __restrict__ cb,
        const float* __restrict__ g, const float* __restrict__ bt,
        const float* __restrict__ lw, const float* __restrict__ lb,
        float* __restrict__ dur) {
    const int row = blockIdx.x * 4 + (threadIdx.x >> 6);
    const int lane = threadIdx.x & 63;
    const float* cr = c + (long)row * F_;
    float2 dv[3];
    dv[0] = ((const float2*)cr)[lane];
    dv[1] = ((const float2*)cr)[lane + 64];
    dv[2] = ((const float2*)cr)[lane + 128];
#pragma unroll
    for (int p = 0; p < 3; ++p) {
        const int ch = 2 * (lane + 64 * p);
        dv[p].x += cb[ch];
        dv[p].y += cb[ch + 1];
    }
    float s = dv[0].x + dv[0].y + dv[1].x + dv[1].y + dv[2].x + dv[2].y;
    float s2 = dv[0].x * dv[0].x + dv[0].y * dv[0].y + dv[1].x * dv[1].x
             + dv[1].y * dv[1].y + dv[2].x * dv[2].x + dv[2].y * dv[2].y;
    for (int off = 32; off >= 1; off >>= 1) {
        s += __shfl_xor(s, off);
        s2 += __shfl_xor(s2, off);
    }
    const float mu = s * (1.f / F_);
    const float var = s2 * (1.f / F_) - mu * mu;
    const float rs = rsqrtf(var + EPS_);
    float dot = 0.f;
#pragma unroll
    for (int p = 0; p < 3; ++p) {
        const int ch = 2 * (lane + 64 * p);
        float r0 = fmaxf((dv[p].x - mu) * rs * g[ch] + bt[ch], 0.f);
        float r1 = fmaxf((dv[p].y - mu) * rs * g[ch + 1] + bt[ch + 1], 0.f);
        dot += r0 * lw[ch] + r1 * lw[ch + 1];
    }
    for (int off = 32; off >= 1; off >>= 1) dot += __shfl_xor(dot, off);
    if (lane == 0) dur[row] = expf(fmaxf(dot + lb[0], 0.f));
}

// ---------------------------------------------------------------------------
// Kernel 6: length-regulate gather (memory bound, unchanged).
// ---------------------------------------------------------------------------
__global__ void k_gather(const float4* __restrict__ x, const int* __restrict__ idx,
                         float4* __restrict__ out) {
    const int F4 = F_ / 4;                        // 96
    const int total = B_ * MAX_OUT_ * F4;
    for (int i = blockIdx.x * blockDim.x + threadIdx.x; i < total;
         i += gridDim.x * blockDim.x) {
        int row = i / F4;
        int f4 = i - row * F4;
        int t = row % MAX_OUT_;
        int b = row / MAX_OUT_;
        int id = idx[b * MAX_OUT_ + t];
        float4 v = make_float4(0.f, 0.f, 0.f, 0.f);
        if (id >= 0) v = x[((long)b * L_ + id) * F4 + f4];
        out[i] = v;
    }
}

// ---------------------------------------------------------------------------
extern "C" void kernel_launch(void* const* d_in, const int* in_sizes, int n_in,
                              void* d_out, int out_size, void* d_ws, size_t ws_size,
                              hipStream_t stream) {
    const float* input   = (const float*)d_in[0];
    const int*   target  = (const int*)d_in[1];
    const float* conv1_w = (const float*)d_in[2];
    const float* conv1_b = (const float*)d_in[3];
    const float* ln1_g   = (const float*)d_in[4];
    const float* ln1_b   = (const float*)d_in[5];
    const float* conv2_w = (const float*)d_in[6];
    const float* conv2_b = (const float*)d_in[7];
    const float* ln2_g   = (const float*)d_in[8];
    const float* ln2_b   = (const float*)d_in[9];
    const float* lin_w   = (const float*)d_in[10];
    const float* lin_b   = (const float*)d_in[11];

    float* out0 = (float*)d_out;                                  // [B, 4096, F]
    float* dur  = out0 + (size_t)B_ * MAX_OUT_ * F_;              // [B, L]
    float* c    = out0;   // raw conv outputs scratched in out0 (overwritten by gather)

    // workspace: idx 256KB + padded x/h1 planes 12.63MB + weight planes 3.54MB
    char* ws = (char*)d_ws;
    int* idx = (int*)ws;                                          // 262144 B
    unsigned short* xh  = (unsigned short*)(ws + 262144);
    unsigned short* xl  = xh + NXP;
    unsigned short* w1h = xl + NXP;
    unsigned short* w1l = w1h + NW;
    unsigned short* w2h = w1l + NW;
    unsigned short* w2l = w2h + NW;

    hipLaunchKernelGGL(k_scan_idx, dim3(B_), dim3(L_), 0, stream, target, idx);
    hipLaunchKernelGGL(k_prep, dim3(2048), dim3(256), 0, stream,
                       input, conv1_w, conv2_w, xh, xl, w1h, w1l, w2h, w2l);
    // conv1: raw output into out0 scratch
    hipLaunchKernelGGL(k_gemm, dim3(M_TOTAL / 64, H_ / 64), dim3(256), 0, stream,
                       xh, xl, w1h, w1l, c);
    // bias+LN+ReLU, re-split into the (now dead) padded x planes
    hipLaunchKernelGGL(k_lnrelu, dim3(M_TOTAL / 4), dim3(256), 0, stream,
                       c, conv1_b, ln1_g, ln1_b, xh, xl);
    // conv2: raw output into out0 scratch
    hipLaunchKernelGGL(k_gemm, dim3(M_TOTAL / 64, H_ / 64), dim3(256), 0, stream,
                       xh, xl, w2h, w2l, c);
    // bias+LN+ReLU+linear+ReLU+exp -> durations
    hipLaunchKernelGGL(k_fin, dim3(M_TOTAL / 4), dim3(256), 0, stream,
                       c, conv2_b, ln2_g, ln2_b, lin_w, lin_b, dur);
    // finally overwrite out0 with the gather
    hipLaunchKernelGGL(k_gather, dim3(4096), dim3(256), 0, stream,
                       (const float4*)input, idx, (float4*)out0);
}

// Round 6
// 101.767 us; speedup vs baseline: 1.6452x; 1.5994x over previous
//
#include <hip/hip_runtime.h>
#include <math.h>

// Problem constants
#define B_ 16
#define L_ 512
#define F_ 384
#define H_ 384
#define K_ 3
#define MAX_OUT_ 4096
#define EPS_ 1e-5f

#define M_TOTAL (B_ * L_)             // 8192 gemm rows
#define KDIM (K_ * F_)                // 1152 gemm K
#define NMB 128                       // 64-row blocks (8192/64)
#define NCG 6                         // 64-col groups (384/64)
#define NST 36                        // K-steps of 32 (1152/32)
// Apack: [m(128)][fstep(12)][row(66)][64B]  (row r -> global l = m*64 + r - 1)
#define APANEL (66 * 64)              // bytes per fstep panel = 4224
#define AMBLK (12 * APANEL)           // bytes per m block = 50688
#define APLANE (NMB * AMBLK)          // 6488064 B per plane
// Bpack: [cg(6)][step(36)][row(64)][64B]
#define BSTEP 4096
#define BCG (NST * BSTEP)             // 147456
#define BPLANE (NCG * BCG)            // 884736 B per plane

typedef __attribute__((ext_vector_type(8))) short bf16x8;   // 8 bf16 = 4 VGPR
typedef __attribute__((ext_vector_type(4))) float f32x4;

// ---------------------------------------------------------------------------
// bf16 split helpers: v = hi + lo with RNE rounding (3-term product error ~2^-17)
// ---------------------------------------------------------------------------
__device__ inline unsigned short bf16_rne(float v) {
    unsigned int u = __float_as_uint(v);
    unsigned int r = (u + 0x7fffu + ((u >> 16) & 1u)) >> 16;
    return (unsigned short)r;
}
__device__ inline void bf16_split(float v, unsigned short& hi, unsigned short& lo) {
    hi = bf16_rne(v);
    float hf = __uint_as_float(((unsigned int)hi) << 16);
    lo = bf16_rne(v - hf);
}

// ---------------------------------------------------------------------------
// Kernel 1: per-batch cumsum of target + searchsorted index table (unchanged).
// ---------------------------------------------------------------------------
__global__ void k_scan_idx(const int* __restrict__ target, int* __restrict__ idx) {
    __shared__ int e[L_];
    const int b = blockIdx.x;
    const int tid = threadIdx.x;   // blockDim = 512 = L_
    e[tid] = target[b * L_ + tid];
    __syncthreads();
    for (int off = 1; off < L_; off <<= 1) {
        int add = (tid >= off) ? e[tid - off] : 0;
        __syncthreads();
        e[tid] += add;
        __syncthreads();
    }
    const int total = e[L_ - 1];
    for (int t = tid; t < MAX_OUT_; t += L_) {
        int lo = 0, hi = L_;
        while (lo < hi) {
            int m = (lo + hi) >> 1;
            if (e[m] <= t) lo = m + 1; else hi = m;
        }
        int v = (t < total) ? min(lo, L_ - 1) : -1;
        idx[b * MAX_OUT_ + t] = v;
    }
}

// ---------------------------------------------------------------------------
// Kernel 2: prep — build LANE-CONTIGUOUS packed operand panels (the LDS image)
// so every k_gemm stage instruction is a contiguous 1KB global_load_lds.
// Chunk permutation p_store = chunk ^ ((row>>1)&3) baked in (bank-spreading;
// read side applies the same XOR -> 2-way banks = free).
// Apack row r of block m = x row l = m*64 + r - 1 (guards zeroed; taps share
// the 66-row window so duplication is only 2/64 rows).
// ---------------------------------------------------------------------------
__global__ void k_prep(const float* __restrict__ x,
                       const float* __restrict__ w1, const float* __restrict__ w2,
                       unsigned short* __restrict__ aph, unsigned short* __restrict__ apl,
                       unsigned short* __restrict__ b1h, unsigned short* __restrict__ b1l,
                       unsigned short* __restrict__ b2h, unsigned short* __restrict__ b2l) {
    const int NA8 = NMB * 12 * 66 * 4;     // 405504 A chunks (16B each)
    const int NB8 = NCG * NST * 64 * 4;    // 55296 B chunks per conv
    const int total = NA8 + 2 * NB8;
    for (int i = blockIdx.x * blockDim.x + threadIdx.x; i < total;
         i += gridDim.x * blockDim.x) {
        if (i < NA8) {
            const int m = i / 3168;            // 12*66*4
            int r1 = i - m * 3168;
            const int fs = r1 / 264;           // 66*4
            int r2 = r1 - fs * 264;
            const int rp = r2 >> 2;
            const int p = r2 & 3;
            const int cgk = p ^ ((rp >> 1) & 3);
            const int f0 = fs * 32 + cgk * 8;
            const int ll = ((m & 7) << 6) + rp - 1;
            ushort4 h0 = {0,0,0,0}, h1 = {0,0,0,0}, l0 = {0,0,0,0}, l1 = {0,0,0,0};
            if (ll >= 0 && ll < L_) {
                const float* src = x + ((size_t)((m >> 3) * L_ + ll) * F_ + f0);
                float4 va = ((const float4*)src)[0];
                float4 vb = ((const float4*)src)[1];
                bf16_split(va.x, h0.x, l0.x); bf16_split(va.y, h0.y, l0.y);
                bf16_split(va.z, h0.z, l0.z); bf16_split(va.w, h0.w, l0.w);
                bf16_split(vb.x, h1.x, l1.x); bf16_split(vb.y, h1.y, l1.y);
                bf16_split(vb.z, h1.z, l1.z); bf16_split(vb.w, h1.w, l1.w);
            }
            ((ushort4*)aph)[i * 2] = h0;  ((ushort4*)aph)[i * 2 + 1] = h1;
            ((ushort4*)apl)[i * 2] = l0;  ((ushort4*)apl)[i * 2 + 1] = l1;
        } else {
            int j = i - NA8;
            const int conv = j / NB8;
            int j2 = j - conv * NB8;
            const float* w = conv ? w2 : w1;
            unsigned short* bh = conv ? b2h : b1h;
            unsigned short* bl = conv ? b2l : b1l;
            const int cg = j2 / 9216;          // 36*64*4
            int r1 = j2 - cg * 9216;
            const int s = r1 / 256;
            int r2 = r1 - s * 256;
            const int rc = r2 >> 2;
            const int p = r2 & 3;
            const int tap = s / 12;
            const int fs = s - tap * 12;
            const int cgk = p ^ ((rc >> 1) & 3);
            const int f0 = fs * 32 + cgk * 8;
            const int h = cg * 64 + rc;
            ushort4 hv0, hv1, lv0, lv1;
            unsigned short th, tl;
#define WSPLIT(E, DH, DL) bf16_split(w[(size_t)(h * F_ + f0 + (E)) * K_ + tap], th, tl); DH = th; DL = tl;
            WSPLIT(0, hv0.x, lv0.x) WSPLIT(1, hv0.y, lv0.y)
            WSPLIT(2, hv0.z, lv0.z) WSPLIT(3, hv0.w, lv0.w)
            WSPLIT(4, hv1.x, lv1.x) WSPLIT(5, hv1.y, lv1.y)
            WSPLIT(6, hv1.z, lv1.z) WSPLIT(7, hv1.w, lv1.w)
#undef WSPLIT
            ((ushort4*)bh)[j2 * 2] = hv0;  ((ushort4*)bh)[j2 * 2 + 1] = hv1;
            ((ushort4*)bl)[j2 * 2] = lv0;  ((ushort4*)bl)[j2 * 2 + 1] = lv1;
        }
    }
}

// ---------------------------------------------------------------------------
// Kernel 3: conv-as-GEMM, split-bf16 MFMA (hh + hl + lh), 64x64 tile, full K.
// 3-buffer LDS pipeline (48KB -> 3 blocks/CU, grid-exact), raw s_barrier +
// counted vmcnt(8): stages stay 3 K-steps (~1000cyc) in flight, never drained
// in-loop. Wave wv stages plane wv (Ah,Al,Bh,Bl) as 4 CONTIGUOUS 1KB
// global_load_lds from the packed panels. ds_reads use the baked chunk-XOR.
// ---------------------------------------------------------------------------
typedef __attribute__((address_space(3))) char lds_char;
typedef const __attribute__((address_space(1))) char g_char;

#define GLDS(gsrc, ldst)                                                   \
    __builtin_amdgcn_global_load_lds((g_char*)(gsrc), (lds_char*)(ldst), 16, 0, 0)

// stage step S into buf S%3: this wave's plane, 4 contiguous 1KB loads
#define ST(S) {                                                            \
    const int off = wvA ? ((((S) % 12) * 66 + (S) / 12) * 64) : ((S) * 4096); \
    _Pragma("unroll")                                                      \
    for (int q = 0; q < 4; ++q)                                            \
        GLDS(srcbase + off + q * 1024,                                     \
             smem + ((S) % 3) * 16384 + wvoff + q * 1024);                 \
}

#define MFMA1(A, Bv, MI, NI)                                               \
    acc[MI][NI] = __builtin_amdgcn_mfma_f32_16x16x32_bf16(A, Bv, acc[MI][NI], 0, 0, 0);

#define STEP(S, NW, DOSTAGE) {                                             \
    asm volatile("s_waitcnt vmcnt(" #NW ")" ::: "memory");                 \
    __builtin_amdgcn_s_barrier();                                          \
    const char* bb = smem + ((S) % 3) * 16384;                             \
    const int tp = (S) / 12;                                               \
    bf16x8 ah0 = *(const bf16x8*)(bb + aadr0[tp]);                         \
    bf16x8 ah1 = *(const bf16x8*)(bb + aadr1[tp]);                         \
    bf16x8 al0 = *(const bf16x8*)(bb + 4096 + aadr0[tp]);                  \
    bf16x8 al1 = *(const bf16x8*)(bb + 4096 + aadr1[tp]);                  \
    bf16x8 bh0 = *(const bf16x8*)(bb + 8192 + badr0);                      \
    bf16x8 bh1 = *(const bf16x8*)(bb + 8192 + badr1);                      \
    bf16x8 bl0 = *(const bf16x8*)(bb + 12288 + badr0);                     \
    bf16x8 bl1 = *(const bf16x8*)(bb + 12288 + badr1);                     \
    asm volatile("s_waitcnt lgkmcnt(0)" ::: "memory");                     \
    __builtin_amdgcn_sched_barrier(0);                                     \
    __builtin_amdgcn_s_barrier();                                          \
    DOSTAGE;                                                               \
    __builtin_amdgcn_s_setprio(1);                                         \
    MFMA1(ah0, bh0, 0, 0) MFMA1(ah0, bh1, 0, 1)                            \
    MFMA1(ah1, bh0, 1, 0) MFMA1(ah1, bh1, 1, 1)                            \
    MFMA1(ah0, bl0, 0, 0) MFMA1(ah0, bl1, 0, 1)                            \
    MFMA1(ah1, bl0, 1, 0) MFMA1(ah1, bl1, 1, 1)                            \
    MFMA1(al0, bh0, 0, 0) MFMA1(al0, bh1, 0, 1)                            \
    MFMA1(al1, bh0, 1, 0) MFMA1(al1, bh1, 1, 1)                            \
    __builtin_amdgcn_s_setprio(0);                                         \
}

__global__ __launch_bounds__(256, 3) void k_gemm(
        const unsigned short* __restrict__ Aph,
        const unsigned short* __restrict__ Apl,
        const unsigned short* __restrict__ Bph,
        const unsigned short* __restrict__ Bpl,
        float* __restrict__ C) {
    __shared__ __align__(1024) char smem[49152];   // 3 bufs x 16 KB
    const int lane = threadIdx.x & 63;
    const int wv = threadIdx.x >> 6;       // wave: stages plane wv
    const int wr = wv >> 1;                // output quadrant row (0,1)
    const int wc = wv & 1;                 // output quadrant col (0,1)
    const int m = blockIdx.x;              // 64-row block
    const int cg = blockIdx.y;             // 64-col group
    const int r0 = m * 64;
    const int h0 = cg * 64;

    const bool wvA = (wv < 2);
    const int wvoff = wv * 4096;
    const char* srcbase;
    {
        const char* ap = (wv == 0) ? (const char*)Aph : (const char*)Apl;
        const char* bp = (wv == 2) ? (const char*)Bph : (const char*)Bpl;
        srcbase = (wvA ? ap + (size_t)m * AMBLK : bp + (size_t)cg * BCG) + lane * 16;
    }

    // fragment read offsets (chunk-XOR matches the packed layout)
    const int fr = lane & 15;
    const int fc = lane >> 4;
    const int rowA0 = wr * 32 + fr, rowA1 = rowA0 + 16;
    const int colB0 = wc * 32 + fr, colB1 = colB0 + 16;
    int aadr0[3], aadr1[3];
#pragma unroll
    for (int t = 0; t < 3; ++t) {
        aadr0[t] = rowA0 * 64 + ((fc ^ (((rowA0 + t) >> 1) & 3)) << 4);
        aadr1[t] = rowA1 * 64 + ((fc ^ (((rowA1 + t) >> 1) & 3)) << 4);
    }
    const int badr0 = colB0 * 64 + ((fc ^ ((colB0 >> 1) & 3)) << 4);
    const int badr1 = colB1 * 64 + ((fc ^ ((colB1 >> 1) & 3)) << 4);

    const f32x4 z4 = {0.f, 0.f, 0.f, 0.f};
    f32x4 acc[2][2];
    acc[0][0] = z4; acc[0][1] = z4; acc[1][0] = z4; acc[1][1] = z4;

    // prologue: 3 stages in flight (12 loads/wave)
    ST(0) ST(1) ST(2)

    STEP(0, 8, ST(3))   STEP(1, 8, ST(4))   STEP(2, 8, ST(5))
    STEP(3, 8, ST(6))   STEP(4, 8, ST(7))   STEP(5, 8, ST(8))
    STEP(6, 8, ST(9))   STEP(7, 8, ST(10))  STEP(8, 8, ST(11))
    STEP(9, 8, ST(12))  STEP(10, 8, ST(13)) STEP(11, 8, ST(14))
    STEP(12, 8, ST(15)) STEP(13, 8, ST(16)) STEP(14, 8, ST(17))
    STEP(15, 8, ST(18)) STEP(16, 8, ST(19)) STEP(17, 8, ST(20))
    STEP(18, 8, ST(21)) STEP(19, 8, ST(22)) STEP(20, 8, ST(23))
    STEP(21, 8, ST(24)) STEP(22, 8, ST(25)) STEP(23, 8, ST(26))
    STEP(24, 8, ST(27)) STEP(25, 8, ST(28)) STEP(26, 8, ST(29))
    STEP(27, 8, ST(30)) STEP(28, 8, ST(31)) STEP(29, 8, ST(32))
    STEP(30, 8, ST(33)) STEP(31, 8, ST(34)) STEP(32, 8, ST(35))
    STEP(33, 8, )       STEP(34, 4, )       STEP(35, 0, )

    // direct C write: C/D layout col = lane&15, row = (lane>>4)*4 + reg
    const int rb = (lane >> 4) * 4;
#pragma unroll
    for (int mi = 0; mi < 2; ++mi)
#pragma unroll
        for (int ni = 0; ni < 2; ++ni)
#pragma unroll
            for (int r = 0; r < 4; ++r)
                C[(size_t)(r0 + wr * 32 + mi * 16 + rb + r) * H_ +
                  h0 + wc * 32 + ni * 16 + fr] = acc[mi][ni][r];
}

// ---------------------------------------------------------------------------
// Kernel 4: bias + LayerNorm + ReLU over raw conv1 output, re-split into the
// PACKED A panels (1-2 slots per row; guard rows stay zero from prep).
// ---------------------------------------------------------------------------
__global__ __launch_bounds__(256) void k_lnrelu(
        const float* __restrict__ c, const float* __restrict__ cb,
        const float* __restrict__ g, const float* __restrict__ bt,
        unsigned short* __restrict__ oh, unsigned short* __restrict__ ol) {
    const int row = blockIdx.x * 4 + (threadIdx.x >> 6);
    const int lane = threadIdx.x & 63;
    const float* cr = c + (size_t)row * H_;
    float2 dv[3];
    dv[0] = ((const float2*)cr)[lane];
    dv[1] = ((const float2*)cr)[lane + 64];
    dv[2] = ((const float2*)cr)[lane + 128];
#pragma unroll
    for (int p = 0; p < 3; ++p) {
        const int ch = 2 * (lane + 64 * p);
        dv[p].x += cb[ch];
        dv[p].y += cb[ch + 1];
    }
    float s = dv[0].x + dv[0].y + dv[1].x + dv[1].y + dv[2].x + dv[2].y;
    float s2 = dv[0].x * dv[0].x + dv[0].y * dv[0].y + dv[1].x * dv[1].x
             + dv[1].y * dv[1].y + dv[2].x * dv[2].x + dv[2].y * dv[2].y;
    for (int off = 32; off >= 1; off >>= 1) {
        s += __shfl_xor(s, off);
        s2 += __shfl_xor(s2, off);
    }
    const float mu = s * (1.f / H_);
    const float var = s2 * (1.f / H_) - mu * mu;
    const float rs = rsqrtf(var + EPS_);
    unsigned short hv[6], lv[6];
#pragma unroll
    for (int p = 0; p < 3; ++p) {
        const int ch = 2 * (lane + 64 * p);
        float r0 = fmaxf((dv[p].x - mu) * rs * g[ch] + bt[ch], 0.f);
        float r1 = fmaxf((dv[p].y - mu) * rs * g[ch + 1] + bt[ch + 1], 0.f);
        bf16_split(r0, hv[2 * p], lv[2 * p]);
        bf16_split(r1, hv[2 * p + 1], lv[2 * p + 1]);
    }
#define WSLOT(M, RP) {                                                        \
    _Pragma("unroll")                                                         \
    for (int p = 0; p < 3; ++p) {                                             \
        const int ch = 2 * (lane + 64 * p);                                   \
        const int fs = ch >> 5;                                               \
        const int k32 = ch & 31;                                              \
        const int pst = (k32 >> 3) ^ (((RP) >> 1) & 3);                       \
        const size_t ix = ((size_t)(((M) * 12 + fs) * 66 + (RP)) * 4 + pst) * 8 + (k32 & 7); \
        *(ushort2*)(oh + ix) = make_ushort2(hv[2 * p], hv[2 * p + 1]);        \
        *(ushort2*)(ol + ix) = make_ushort2(lv[2 * p], lv[2 * p + 1]);        \
    }                                                                         \
}
    const int m1 = row >> 6;
    const int rsub = row & 63;
    WSLOT(m1, rsub + 1);
    if (rsub == 0 && (row & 511) != 0)   WSLOT(m1 - 1, 65);
    if (rsub == 63 && (row & 511) != 511) WSLOT(m1 + 1, 0);
#undef WSLOT
}

// ---------------------------------------------------------------------------
// Kernel 5: bias + LayerNorm + ReLU + linear + ReLU + exp -> durations.
// ---------------------------------------------------------------------------
__global__ __launch_bounds__(256) void k_fin(
        const float* __restrict__ c, const float* __restrict__ cb,
        const float* __restrict__ g, const float* __restrict__ bt,
        const float* __restrict__ lw, const float* __restrict__ lb,
        float* __restrict__ dur) {
    const int row = blockIdx.x * 4 + (threadIdx.x >> 6);
    const int lane = threadIdx.x & 63;
    const float* cr = c + (size_t)row * F_;
    float2 dv[3];
    dv[0] = ((const float2*)cr)[lane];
    dv[1] = ((const float2*)cr)[lane + 64];
    dv[2] = ((const float2*)cr)[lane + 128];
#pragma unroll
    for (int p = 0; p < 3; ++p) {
        const int ch = 2 * (lane + 64 * p);
        dv[p].x += cb[ch];
        dv[p].y += cb[ch + 1];
    }
    float s = dv[0].x + dv[0].y + dv[1].x + dv[1].y + dv[2].x + dv[2].y;
    float s2 = dv[0].x * dv[0].x + dv[0].y * dv[0].y + dv[1].x * dv[1].x
             + dv[1].y * dv[1].y + dv[2].x * dv[2].x + dv[2].y * dv[2].y;
    for (int off = 32; off >= 1; off >>= 1) {
        s += __shfl_xor(s, off);
        s2 += __shfl_xor(s2, off);
    }
    const float mu = s * (1.f / F_);
    const float var = s2 * (1.f / F_) - mu * mu;
    const float rs = rsqrtf(var + EPS_);
    float dot = 0.f;
#pragma unroll
    for (int p = 0; p < 3; ++p) {
        const int ch = 2 * (lane + 64 * p);
        float r0 = fmaxf((dv[p].x - mu) * rs * g[ch] + bt[ch], 0.f);
        float r1 = fmaxf((dv[p].y - mu) * rs * g[ch + 1] + bt[ch + 1], 0.f);
        dot += r0 * lw[ch] + r1 * lw[ch + 1];
    }
    for (int off = 32; off >= 1; off >>= 1) dot += __shfl_xor(dot, off);
    if (lane == 0) dur[row] = expf(fmaxf(dot + lb[0], 0.f));
}

// ---------------------------------------------------------------------------
// Kernel 6: length-regulate gather (memory bound, unchanged).
// ---------------------------------------------------------------------------
__global__ void k_gather(const float4* __restrict__ x, const int* __restrict__ idx,
                         float4* __restrict__ out) {
    const int F4 = F_ / 4;                        // 96
    const int total = B_ * MAX_OUT_ * F4;
    for (int i = blockIdx.x * blockDim.x + threadIdx.x; i < total;
         i += gridDim.x * blockDim.x) {
        int row = i / F4;
        int f4 = i - row * F4;
        int t = row % MAX_OUT_;
        int b = row / MAX_OUT_;
        int id = idx[b * MAX_OUT_ + t];
        float4 v = make_float4(0.f, 0.f, 0.f, 0.f);
        if (id >= 0) v = x[((size_t)b * L_ + id) * F4 + f4];
        out[i] = v;
    }
}

// ---------------------------------------------------------------------------
extern "C" void kernel_launch(void* const* d_in, const int* in_sizes, int n_in,
                              void* d_out, int out_size, void* d_ws, size_t ws_size,
                              hipStream_t stream) {
    const float* input   = (const float*)d_in[0];
    const int*   target  = (const int*)d_in[1];
    const float* conv1_w = (const float*)d_in[2];
    const float* conv1_b = (const float*)d_in[3];
    const float* ln1_g   = (const float*)d_in[4];
    const float* ln1_b   = (const float*)d_in[5];
    const float* conv2_w = (const float*)d_in[6];
    const float* conv2_b = (const float*)d_in[7];
    const float* ln2_g   = (const float*)d_in[8];
    const float* ln2_b   = (const float*)d_in[9];
    const float* lin_w   = (const float*)d_in[10];
    const float* lin_b   = (const float*)d_in[11];

    float* out0 = (float*)d_out;                                  // [B, 4096, F]
    float* dur  = out0 + (size_t)B_ * MAX_OUT_ * F_;              // [B, L]
    float* c    = out0;   // raw conv outputs [8192][384] f32 (overwritten by gather)
    // Big A packs live in d_out's unused tail (100.7MB total; c ends at 12.6MB;
    // everything below dur is overwritten by the final gather).
    char* ob = (char*)d_out;
    unsigned short* aph = (unsigned short*)(ob + (16u << 20));    // 6.49MB
    unsigned short* apl = (unsigned short*)(ob + (24u << 20));    // 6.49MB

    // workspace: idx 256KB + B packs 3.54MB
    char* ws = (char*)d_ws;
    int* idx = (int*)ws;                                          // 262144 B
    unsigned short* b1h = (unsigned short*)(ws + 262144);
    unsigned short* b1l = b1h + BPLANE / 2;
    unsigned short* b2h = b1l + BPLANE / 2;
    unsigned short* b2l = b2h + BPLANE / 2;

    hipLaunchKernelGGL(k_scan_idx, dim3(B_), dim3(L_), 0, stream, target, idx);
    hipLaunchKernelGGL(k_prep, dim3(2048), dim3(256), 0, stream,
                       input, conv1_w, conv2_w, aph, apl, b1h, b1l, b2h, b2l);
    // conv1: raw output into out0 scratch
    hipLaunchKernelGGL(k_gemm, dim3(NMB, NCG), dim3(256), 0, stream,
                       aph, apl, b1h, b1l, c);
    // bias+LN+ReLU, re-split into the packed A panels (guards stay zero)
    hipLaunchKernelGGL(k_lnrelu, dim3(M_TOTAL / 4), dim3(256), 0, stream,
                       c, conv1_b, ln1_g, ln1_b, aph, apl);
    // conv2: raw output into out0 scratch
    hipLaunchKernelGGL(k_gemm, dim3(NMB, NCG), dim3(256), 0, stream,
                       aph, apl, b2h, b2l, c);
    // bias+LN+ReLU+linear+ReLU+exp -> durations
    hipLaunchKernelGGL(k_fin, dim3(M_TOTAL / 4), dim3(256), 0, stream,
                       c, conv2_b, ln2_g, ln2_b, lin_w, lin_b, dur);
    // finally overwrite out0 with the gather
    hipLaunchKernelGGL(k_gather, dim3(4096), dim3(256), 0, stream,
                       (const float4*)input, idx, (float4*)out0);
}